// Round 6
// baseline (886.884 us; speedup 1.0000x reference)
//
#include <hip/hip_runtime.h>

// SpikeFP32GELUExact: input  x [B=2, S=2048, D=1024, 32] float32 0/1 pulses (MSB-first bits of f32)
//                     output same shape: pulses of fp32(GELU_fp64(value))
// One thread per value: pack 32 pulses -> u32 -> f32 -> f64 GELU (exact formula,
// contraction OFF to match the reference's separate mul/add) -> f32 -> unpack 32 pulses.

__global__ __launch_bounds__(256) void spike_gelu_kernel(const float* __restrict__ in,
                                                         float* __restrict__ out,
                                                         int nvals) {
    int v = blockIdx.x * blockDim.x + threadIdx.x;
    if (v >= nvals) return;

    const float4* __restrict__ in4 = reinterpret_cast<const float4*>(in) + (size_t)v * 8;
    float4* __restrict__ out4 = reinterpret_cast<float4*>(out) + (size_t)v * 8;

    // ---- pack 32 pulses (MSB first) into u32 ----
    unsigned int u = 0u;
#pragma unroll
    for (int k = 0; k < 8; ++k) {
        float4 f = in4[k];
        unsigned int b0 = (f.x != 0.0f) ? 1u : 0u;
        unsigned int b1 = (f.y != 0.0f) ? 1u : 0u;
        unsigned int b2 = (f.z != 0.0f) ? 1u : 0u;
        unsigned int b3 = (f.w != 0.0f) ? 1u : 0u;
        u |= (b0 << (31 - 4 * k)) | (b1 << (30 - 4 * k)) |
             (b2 << (29 - 4 * k)) | (b3 << (28 - 4 * k));
    }

    // ---- exact-FP64 GELU, matching the reference op-for-op ----
    // Disable FMA contraction: reference does separate mul then add in f64.
    {
#pragma clang fp contract(off)
        float xf = __uint_as_float(u);
        double vd = (double)xf;                       // exact f32->f64
        double x_sq = vd * vd;
        double x_cubed = x_sq * vd;
        double inner = vd + 0.044715 * x_cubed;
        double z = 0.7978845608028654 * inner;
        double e2z = exp(2.0 * z);                    // 2.0*z exact (pow2 scale)
        double tanh_z = (e2z - 1.0) / (e2z + 1.0);
        double res64 = 0.5 * (vd * (1.0 + tanh_z));
        float rf = (float)res64;                      // IEEE RN downcast
        u = __float_as_uint(rf);
    }

    // ---- unpack result bits to 32 pulses (MSB first) ----
#pragma unroll
    for (int k = 0; k < 8; ++k) {
        float4 o;
        o.x = (float)((u >> (31 - 4 * k)) & 1u);
        o.y = (float)((u >> (30 - 4 * k)) & 1u);
        o.z = (float)((u >> (29 - 4 * k)) & 1u);
        o.w = (float)((u >> (28 - 4 * k)) & 1u);
        out4[k] = o;
    }
}

extern "C" void kernel_launch(void* const* d_in, const int* in_sizes, int n_in,
                              void* d_out, int out_size, void* d_ws, size_t ws_size,
                              hipStream_t stream) {
    const float* x = (const float*)d_in[0];
    float* out = (float*)d_out;
    int nvals = out_size / 32;                        // 4,194,304 values
    int block = 256;
    int grid = (nvals + block - 1) / block;           // 16384 blocks
    spike_gelu_kernel<<<grid, block, 0, stream>>>(x, out, nvals);
}

// Round 7
// 836.288 us; speedup vs baseline: 1.0605x; 1.0605x over previous
//
#include <hip/hip_runtime.h>

// SpikeFP32GELUExact: x [2,2048,1024,32] f32 0/1 pulses (MSB-first bits of f32) ->
// pulses of fp32(GELU_fp64(value)).
//
// R6 post-mortem: one-thread-per-value with per-thread 128B-contiguous accesses
// made every VMEM instruction 64-way line-divergent (~520 cyc/instr, 1.2 TB/s).
// This version keeps one value per thread but transposes in-register:
// all global loads/stores are wave-coalesced float4 (1KB/instr); the bit<->value
// redistribution uses __shfl_xor OR-reduce (pack) and __shfl (unpack). No LDS.

__global__ __launch_bounds__(256) void spike_gelu_kernel(const float* __restrict__ in,
                                                         float* __restrict__ out,
                                                         int nvals) {
    const int tid  = blockIdx.x * blockDim.x + threadIdx.x;
    const int lane = threadIdx.x & 63;
    const int wave = tid >> 6;                 // each wave: 64 values = 2048 floats
    if (wave * 64 >= nvals) return;            // wave-granular guard (sizes are x64)

    const size_t base4 = (size_t)wave * 512;   // float4 offset of this wave's span
    const float4* __restrict__ in4 = reinterpret_cast<const float4*>(in) + base4;
    float4* __restrict__ out4      = reinterpret_cast<float4*>(out) + base4;

    const int c  = lane & 7;                   // nibble index within a value
    const int s0 = 31 - 4 * c;                 // MSB-first shift for this nibble

    // ---- pack: 8 coalesced rounds; lane ends holding value v(l)=8*(l&7)+(l>>3) ----
    unsigned int u = 0u;
#pragma unroll
    for (int r = 0; r < 8; ++r) {
        float4 f = in4[r * 64 + lane];         // coalesced: 64 lanes x 16B contiguous
        unsigned int partial =
              ((unsigned int)f.x << s0)        // pulses are exactly 0.0f/1.0f
            | ((unsigned int)f.y << (s0 - 1))
            | ((unsigned int)f.z << (s0 - 2))
            | ((unsigned int)f.w << (s0 - 3));
        partial |= __shfl_xor(partial, 1);     // OR-reduce within 8-lane group:
        partial |= __shfl_xor(partial, 2);     // group g=lane>>3 builds value 8r+g
        partial |= __shfl_xor(partial, 4);
        if (c == r) u = partial;               // keep -> bijective lane->value map
    }

    // ---- exact-FP64 GELU, matching the reference op-for-op ----
    {
#pragma clang fp contract(off)
        float xf = __uint_as_float(u);
        double vd = (double)xf;                // exact f32->f64
        double x_sq = vd * vd;
        double x_cubed = x_sq * vd;
        double inner = vd + 0.044715 * x_cubed;
        double z = 0.7978845608028654 * inner;
        double e2z = exp(2.0 * z);             // 2.0*z exact (pow2 scale)
        double tanh_z = (e2z - 1.0) / (e2z + 1.0);
        double res64 = 0.5 * (vd * (1.0 + tanh_z));
        float rf = (float)res64;               // IEEE RN downcast
        u = __float_as_uint(rf);
    }

    // ---- unpack: 8 coalesced rounds; fetch value 8r+(l>>3) from lane (l&56)|r ----
#pragma unroll
    for (int r = 0; r < 8; ++r) {
        unsigned int w = (unsigned int)__shfl((int)u, (lane & 56) | r);
        float4 o;
        o.x = (float)((w >> s0) & 1u);
        o.y = (float)((w >> (s0 - 1)) & 1u);
        o.z = (float)((w >> (s0 - 2)) & 1u);
        o.w = (float)((w >> (s0 - 3)) & 1u);
        out4[r * 64 + lane] = o;               // coalesced 1KB per wave
    }
}

extern "C" void kernel_launch(void* const* d_in, const int* in_sizes, int n_in,
                              void* d_out, int out_size, void* d_ws, size_t ws_size,
                              hipStream_t stream) {
    const float* x = (const float*)d_in[0];
    float* out = (float*)d_out;
    int nvals = out_size / 32;                 // 4,194,304 values
    int block = 256;
    int grid = (nvals + block - 1) / block;    // 16384 blocks, 4 waves each
    spike_gelu_kernel<<<grid, block, 0, stream>>>(x, out, nvals);
}